// Round 1
// baseline (233.213 us; speedup 1.0000x reference)
//
#include <hip/hip_runtime.h>

#define CLASS_NUM 19
#define NBINS (CLASS_NUM * CLASS_NUM)   // 361
#define HW (512 * 512)                  // 262144 = 2^18
#define NPIX (8 * HW)                   // 2097152
#define NVEC (NPIX / 4)                 // 524288
#define HWV (HW / 4)                    // 65536 = 2^16

__global__ void zero_out_kernel(int* __restrict__ out) {
    int t = threadIdx.x;
    if (t < NBINS) out[t] = 0;
}

__global__ __launch_bounds__(256) void confusion_kernel(
    const float4* __restrict__ in,   // [B, C, HW/4] as float4
    const int4*  __restrict__ tgt,   // [B, HW/4] as int4
    int* __restrict__ out)           // [361]
{
    __shared__ int hist[NBINS];
    for (int i = threadIdx.x; i < NBINS; i += blockDim.x) hist[i] = 0;
    __syncthreads();

    const int stride = gridDim.x * blockDim.x;
    for (int g = blockIdx.x * blockDim.x + threadIdx.x; g < NVEC; g += stride) {
        int b   = g >> 16;          // g / HWV
        int hwv = g & (HWV - 1);    // g % HWV
        const float4* p = in + (size_t)(b * CLASS_NUM) * HWV + hwv;

        float4 best = p[0];
        int bx = 0, by = 0, bz = 0, bw = 0;
        #pragma unroll
        for (int c = 1; c < CLASS_NUM; ++c) {
            float4 v = p[(size_t)c * HWV];
            if (v.x > best.x) { best.x = v.x; bx = c; }
            if (v.y > best.y) { best.y = v.y; by = c; }
            if (v.z > best.z) { best.z = v.z; bz = c; }
            if (v.w > best.w) { best.w = v.w; bw = c; }
        }

        int4 t = tgt[g];
        atomicAdd(&hist[t.x * CLASS_NUM + bx], 1);
        atomicAdd(&hist[t.y * CLASS_NUM + by], 1);
        atomicAdd(&hist[t.z * CLASS_NUM + bz], 1);
        atomicAdd(&hist[t.w * CLASS_NUM + bw], 1);
    }

    __syncthreads();
    for (int i = threadIdx.x; i < NBINS; i += blockDim.x) {
        int v = hist[i];
        if (v) atomicAdd(&out[i], v);
    }
}

extern "C" void kernel_launch(void* const* d_in, const int* in_sizes, int n_in,
                              void* d_out, int out_size, void* d_ws, size_t ws_size,
                              hipStream_t stream) {
    const float4* in  = (const float4*)d_in[0];
    const int4*   tgt = (const int4*)d_in[1];
    int* out = (int*)d_out;

    // d_out is poisoned 0xAA before every timed launch — zero it first.
    zero_out_kernel<<<1, 512, 0, stream>>>(out);

    // 1024 blocks x 256 threads = 262144 threads; each handles 2 float4 pixel-quads.
    confusion_kernel<<<1024, 256, 0, stream>>>(in, tgt, out);
}

// Round 2
// 230.095 us; speedup vs baseline: 1.0136x; 1.0136x over previous
//
#include <hip/hip_runtime.h>

#define CLASS_NUM 19
#define NBINS (CLASS_NUM * CLASS_NUM)   // 361
#define HW (512 * 512)                  // 262144
#define NPIX (8 * HW)                   // 2097152
#define NVEC (NPIX / 4)                 // 524288 pixel-quads
#define HWV (HW / 4)                    // 65536 float4 per channel-image

__global__ void zero_out_kernel(int* __restrict__ out) {
    int t = threadIdx.x;
    if (t < NBINS) out[t] = 0;
}

// One pixel-quad per thread: 1024 blocks x 512 threads = 524288 threads.
// All 19 channel loads are issued into a register array before the compare
// tree so the memory pipe sees 19 independent dwordx4 loads per lane.
__global__ __launch_bounds__(512, 4) void confusion_kernel(
    const float4* __restrict__ in,   // [B, C, HWV] as float4
    const int4*  __restrict__ tgt,   // [B, HWV] as int4
    int* __restrict__ out)           // [361]
{
    __shared__ int hist[NBINS];
    for (int i = threadIdx.x; i < NBINS; i += 512) hist[i] = 0;
    __syncthreads();

    const int g   = blockIdx.x * 512 + threadIdx.x;   // [0, NVEC)
    const int b   = g >> 16;                          // g / HWV
    const int hwv = g & (HWV - 1);                    // g % HWV
    const float4* p = in + (size_t)b * (CLASS_NUM * HWV) + hwv;

    float4 v[CLASS_NUM];
    #pragma unroll
    for (int c = 0; c < CLASS_NUM; ++c) v[c] = p[(size_t)c * HWV];

    float4 best = v[0];
    int bx = 0, by = 0, bz = 0, bw = 0;
    #pragma unroll
    for (int c = 1; c < CLASS_NUM; ++c) {
        if (v[c].x > best.x) { best.x = v[c].x; bx = c; }
        if (v[c].y > best.y) { best.y = v[c].y; by = c; }
        if (v[c].z > best.z) { best.z = v[c].z; bz = c; }
        if (v[c].w > best.w) { best.w = v[c].w; bw = c; }
    }

    const int4 t = tgt[g];
    atomicAdd(&hist[t.x * CLASS_NUM + bx], 1);
    atomicAdd(&hist[t.y * CLASS_NUM + by], 1);
    atomicAdd(&hist[t.z * CLASS_NUM + bz], 1);
    atomicAdd(&hist[t.w * CLASS_NUM + bw], 1);

    __syncthreads();
    for (int i = threadIdx.x; i < NBINS; i += 512) {
        int h = hist[i];
        if (h) atomicAdd(&out[i], h);
    }
}

extern "C" void kernel_launch(void* const* d_in, const int* in_sizes, int n_in,
                              void* d_out, int out_size, void* d_ws, size_t ws_size,
                              hipStream_t stream) {
    const float4* in  = (const float4*)d_in[0];
    const int4*   tgt = (const int4*)d_in[1];
    int* out = (int*)d_out;

    // d_out is re-poisoned to 0xAA before every timed launch — zero it first.
    zero_out_kernel<<<1, 512, 0, stream>>>(out);

    confusion_kernel<<<NVEC / 512, 512, 0, stream>>>(in, tgt, out);
}